// Round 1
// baseline (3099.721 us; speedup 1.0000x reference)
//
#include <hip/hip_runtime.h>
#include <math.h>

#define BB 4096
#define TT 48
#define FF 64
#define HH 128
#define ROWS 16
#define NT 256

__device__ __forceinline__ float dot4(float4 w, float4 v) {
    return fmaf(w.x, v.x, fmaf(w.y, v.y, fmaf(w.z, v.z, w.w * v.w)));
}
__device__ __forceinline__ float sigm(float x) { return 1.f / (1.f + __expf(-x)); }
__device__ __forceinline__ float tanh_f(float x) { return 2.f / (1.f + __expf(-2.f * x)) - 1.f; }

// Kernel 1: denom[t] = sum over (B,F) of masks[:,t,:] + 1e-5 ; also zero the loss slot.
__global__ __launch_bounds__(NT) void denom_kernel(const float* __restrict__ masks,
                                                   float* __restrict__ denom,
                                                   float* __restrict__ out_loss) {
    const int t = blockIdx.x;
    const int tid = threadIdx.x;
    float s = 0.f;
    for (int i = tid; i < BB * FF; i += NT) {
        int b = i >> 6, f = i & 63;
        s += masks[(b * TT + t) * FF + f];
    }
    #pragma unroll
    for (int off = 32; off; off >>= 1) s += __shfl_down(s, off, 64);
    __shared__ float red[NT / 64];
    if ((tid & 63) == 0) red[tid >> 6] = s;
    __syncthreads();
    if (tid == 0) {
        float tot = 0.f;
        #pragma unroll
        for (int w = 0; w < NT / 64; ++w) tot += red[w];
        denom[t] = tot + 1e-5f;
        if (t == 0) out_loss[0] = 0.f;
    }
}

// Main persistent kernel: each block owns ROWS batch rows, iterates all T steps.
__global__ __launch_bounds__(NT, 1) void rits_kernel(
    const float* __restrict__ values, const float* __restrict__ masks,
    const float* __restrict__ deltas,
    const float* __restrict__ Wdh, const float* __restrict__ bdh,
    const float* __restrict__ Wdx, const float* __restrict__ bdx,
    const float* __restrict__ Wh,  const float* __restrict__ bh,
    const float* __restrict__ Wf,  const float* __restrict__ bf,
    const float* __restrict__ Wc,  const float* __restrict__ bc,
    const float* __restrict__ W_ih, const float* __restrict__ W_hh,
    const float* __restrict__ b_ih, const float* __restrict__ b_hh,
    const float* __restrict__ Wo,  const float* __restrict__ bo,
    const float* __restrict__ denom,
    float* __restrict__ out_loss, float* __restrict__ out_imp,
    float* __restrict__ out_pred)
{
    __shared__ float h_lds[ROWS][HH];     // decayed hidden state
    __shared__ float x_lds[ROWS][FF];     // x; becomes c_c after phase 6
    __shared__ float m_lds[ROWS][FF];     // mask
    __shared__ float d_lds[ROWS][FF];     // delta; becomes x_c after phase 4
    __shared__ float xh_lds[ROWS][FF];    // x_h
    __shared__ float zh_lds[ROWS][FF];    // z_h
    __shared__ float gx_lds[ROWS][FF];    // gamma_x
    __shared__ float wfT[FF][FF];         // Wf transposed: wfT[k][f] = Wf[f][k]
    __shared__ float red_l[NT / 64];

    const int tid = threadIdx.x;
    const int b0 = blockIdx.x * ROWS;

    // stage Wf transposed (one-time; write conflicts negligible)
    for (int i = tid; i < FF * FF; i += NT) {
        int f = i >> 6, k = i & 63;
        wfT[k][f] = Wf[i];
    }
    for (int i = tid; i < ROWS * HH; i += NT) ((float*)h_lds)[i] = 0.f;

    // per-thread fixed indices: j for H-dim phases, f for F-dim phases
    const int j   = tid & 127;
    const int jr0 = tid >> 7;   // 0..1 ; rows jr0 + 2q (q=0..7)
    const int f   = tid & 63;
    const int fr0 = tid >> 6;   // 0..3 ; rows fr0 + 4q (q=0..3)

    const float bdh_j = bdh[j];
    const float bdx_f = bdx[f];
    const float wdx_f = Wdx[f * FF + f];   // diagonal entry
    const float bh_f  = bh[f];
    const float bf_f  = bf[f];
    const float wf_dg = Wf[f * FF + f];    // diagonal to subtract (Wf_m has zero diag)
    const float bc_f  = bc[f];
    float bg0 = b_ih[0 * HH + j] + b_hh[0 * HH + j];
    float bg1 = b_ih[1 * HH + j] + b_hh[1 * HH + j];
    float bg2 = b_ih[2 * HH + j] + b_hh[2 * HH + j];
    float bg3 = b_ih[3 * HH + j] + b_hh[3 * HH + j];

    float c_reg[8];
    #pragma unroll
    for (int q = 0; q < 8; ++q) c_reg[q] = 0.f;

    float loss_local = 0.f;

    __syncthreads();

    for (int t = 0; t < TT; ++t) {
        const float invd = 1.0f / denom[t];

        // ---- phase 1: load x, m, d ; gamma_x (diag decay) ----
        #pragma unroll
        for (int q = 0; q < 4; ++q) {
            const int r = fr0 + 4 * q;
            const int off = ((b0 + r) * TT + t) * FF + f;
            const float xv = values[off], mv = masks[off], dv = deltas[off];
            x_lds[r][f] = xv;
            m_lds[r][f] = mv;
            d_lds[r][f] = dv;
            gx_lds[r][f] = __expf(-fmaxf(fmaf(dv, wdx_f, bdx_f), 0.f));
        }
        __syncthreads();

        // ---- phase 3: gamma_h = exp(-relu(d @ Wdh.T + bdh)); h *= gamma_h ----
        {
            float acc[8];
            #pragma unroll
            for (int q = 0; q < 8; ++q) acc[q] = 0.f;
            const float4* w4 = (const float4*)(Wdh + j * FF);
            #pragma unroll 4
            for (int kk = 0; kk < 16; ++kk) {
                const float4 w = w4[kk];
                #pragma unroll
                for (int q = 0; q < 8; ++q) {
                    const int r = jr0 + 2 * q;
                    const float4 dv = *(const float4*)&d_lds[r][kk * 4];
                    acc[q] += dot4(w, dv);
                }
            }
            #pragma unroll
            for (int q = 0; q < 8; ++q) {
                const int r = jr0 + 2 * q;
                const float gh = __expf(-fmaxf(acc[q] + bdh_j, 0.f));
                h_lds[r][j] *= gh;
            }
        }
        __syncthreads();

        float stepsum = 0.f;

        // ---- phase 4: x_h = h @ Wh.T + bh ; loss1 ; x_c -> d_lds ----
        {
            float acc[4];
            #pragma unroll
            for (int q = 0; q < 4; ++q) acc[q] = 0.f;
            const float4* w4 = (const float4*)(Wh + f * HH);
            #pragma unroll 4
            for (int kk = 0; kk < 32; ++kk) {
                const float4 w = w4[kk];
                #pragma unroll
                for (int q = 0; q < 4; ++q) {
                    const int r = fr0 + 4 * q;
                    const float4 hv = *(const float4*)&h_lds[r][kk * 4];
                    acc[q] += dot4(w, hv);
                }
            }
            #pragma unroll
            for (int q = 0; q < 4; ++q) {
                const int r = fr0 + 4 * q;
                const float xh = acc[q] + bh_f;
                xh_lds[r][f] = xh;
                const float xv = x_lds[r][f], mv = m_lds[r][f];
                stepsum += mv * fabsf(xv - xh);
                d_lds[r][f] = fmaf(mv, xv, (1.f - mv) * xh);  // x_c
            }
        }
        __syncthreads();

        // ---- phase 5: z_h = x_c @ Wf_m.T + bf (zero diag) ; loss2 ----
        {
            float acc[4];
            #pragma unroll
            for (int q = 0; q < 4; ++q) acc[q] = 0.f;
            for (int k = 0; k < FF; ++k) {
                const float w = wfT[k][f];
                #pragma unroll
                for (int q = 0; q < 4; ++q) acc[q] = fmaf(d_lds[fr0 + 4 * q][k], w, acc[q]);
            }
            #pragma unroll
            for (int q = 0; q < 4; ++q) {
                const int r = fr0 + 4 * q;
                const float zh = acc[q] + bf_f - d_lds[r][f] * wf_dg;
                zh_lds[r][f] = zh;
                stepsum += m_lds[r][f] * fabsf(x_lds[r][f] - zh);
            }
        }
        __syncthreads();

        // ---- phase 6: alpha = [gamma_x, m] @ Wc.T + bc ; c_h ; loss3 ; c_c ----
        {
            float acc[4];
            #pragma unroll
            for (int q = 0; q < 4; ++q) acc[q] = 0.f;
            const float4* wc4 = (const float4*)(Wc + f * 2 * FF);
            #pragma unroll 4
            for (int kk = 0; kk < 16; ++kk) {
                const float4 w = wc4[kk];
                #pragma unroll
                for (int q = 0; q < 4; ++q) {
                    const float4 g4 = *(const float4*)&gx_lds[fr0 + 4 * q][kk * 4];
                    acc[q] += dot4(w, g4);
                }
            }
            #pragma unroll 4
            for (int kk = 0; kk < 16; ++kk) {
                const float4 w = wc4[16 + kk];
                #pragma unroll
                for (int q = 0; q < 4; ++q) {
                    const float4 m4 = *(const float4*)&m_lds[fr0 + 4 * q][kk * 4];
                    acc[q] += dot4(w, m4);
                }
            }
            #pragma unroll
            for (int q = 0; q < 4; ++q) {
                const int r = fr0 + 4 * q;
                const float alpha = acc[q] + bc_f;
                const float ch = fmaf(alpha, zh_lds[r][f], (1.f - alpha) * xh_lds[r][f]);
                const float xv = x_lds[r][f], mv = m_lds[r][f];
                stepsum += mv * fabsf(xv - ch);
                const float cc = fmaf(mv, xv, (1.f - mv) * ch);
                x_lds[r][f] = cc;  // becomes LSTM input c_c
                out_imp[((b0 + r) * TT + t) * FF + f] = cc;
            }
        }
        loss_local += stepsum * invd;
        __syncthreads();

        // ---- phase 7: gates = [c_c,m]@W_ih.T + b_ih + h@W_hh.T + b_hh ; LSTM ----
        {
            float a0[8], a1[8], a2[8], a3[8];
            #pragma unroll
            for (int q = 0; q < 8; ++q) { a0[q] = bg0; a1[q] = bg1; a2[q] = bg2; a3[q] = bg3; }
            const float4* wi0 = (const float4*)(W_ih + (0 * HH + j) * 2 * FF);
            const float4* wi1 = (const float4*)(W_ih + (1 * HH + j) * 2 * FF);
            const float4* wi2 = (const float4*)(W_ih + (2 * HH + j) * 2 * FF);
            const float4* wi3 = (const float4*)(W_ih + (3 * HH + j) * 2 * FF);
            #pragma unroll 4
            for (int kk = 0; kk < 16; ++kk) {  // c_c half (k=0..63)
                const float4 w0 = wi0[kk], w1 = wi1[kk], w2 = wi2[kk], w3 = wi3[kk];
                #pragma unroll
                for (int q = 0; q < 8; ++q) {
                    const float4 v = *(const float4*)&x_lds[jr0 + 2 * q][kk * 4];
                    a0[q] += dot4(w0, v); a1[q] += dot4(w1, v);
                    a2[q] += dot4(w2, v); a3[q] += dot4(w3, v);
                }
            }
            #pragma unroll 4
            for (int kk = 0; kk < 16; ++kk) {  // m half (k=64..127)
                const float4 w0 = wi0[16 + kk], w1 = wi1[16 + kk], w2 = wi2[16 + kk], w3 = wi3[16 + kk];
                #pragma unroll
                for (int q = 0; q < 8; ++q) {
                    const float4 v = *(const float4*)&m_lds[jr0 + 2 * q][kk * 4];
                    a0[q] += dot4(w0, v); a1[q] += dot4(w1, v);
                    a2[q] += dot4(w2, v); a3[q] += dot4(w3, v);
                }
            }
            const float4* wh0 = (const float4*)(W_hh + (0 * HH + j) * HH);
            const float4* wh1 = (const float4*)(W_hh + (1 * HH + j) * HH);
            const float4* wh2 = (const float4*)(W_hh + (2 * HH + j) * HH);
            const float4* wh3 = (const float4*)(W_hh + (3 * HH + j) * HH);
            #pragma unroll 4
            for (int kk = 0; kk < 32; ++kk) {  // h part (k=0..127)
                const float4 w0 = wh0[kk], w1 = wh1[kk], w2 = wh2[kk], w3 = wh3[kk];
                #pragma unroll
                for (int q = 0; q < 8; ++q) {
                    const float4 v = *(const float4*)&h_lds[jr0 + 2 * q][kk * 4];
                    a0[q] += dot4(w0, v); a1[q] += dot4(w1, v);
                    a2[q] += dot4(w2, v); a3[q] += dot4(w3, v);
                }
            }
            float hnew[8];
            #pragma unroll
            for (int q = 0; q < 8; ++q) {
                const float ig = sigm(a0[q]);
                const float fg = sigm(a1[q]);
                const float gg = tanh_f(a2[q]);
                const float og = sigm(a3[q]);
                c_reg[q] = fmaf(fg, c_reg[q], ig * gg);
                hnew[q] = og * tanh_f(c_reg[q]);
            }
            __syncthreads();  // all reads of old h done before overwrite
            #pragma unroll
            for (int q = 0; q < 8; ++q) h_lds[jr0 + 2 * q][j] = hnew[q];
        }
        __syncthreads();
    }

    // ---- predictions: h @ Wo.T + bo ----
    {
        const int r = tid >> 4, l = tid & 15;
        float s = 0.f;
        for (int k = l; k < HH; k += 16) s += h_lds[r][k] * Wo[k];
        #pragma unroll
        for (int off = 8; off; off >>= 1) s += __shfl_down(s, off, 16);
        if (l == 0) out_pred[b0 + r] = s + bo[0];
    }

    // ---- loss reduce + atomic ----
    #pragma unroll
    for (int off = 32; off; off >>= 1) loss_local += __shfl_down(loss_local, off, 64);
    if ((tid & 63) == 0) red_l[tid >> 6] = loss_local;
    __syncthreads();
    if (tid == 0) {
        float tot = 0.f;
        #pragma unroll
        for (int w = 0; w < NT / 64; ++w) tot += red_l[w];
        atomicAdd(out_loss, tot);
    }
}

extern "C" void kernel_launch(void* const* d_in, const int* in_sizes, int n_in,
                              void* d_out, int out_size, void* d_ws, size_t ws_size,
                              hipStream_t stream) {
    const float* values = (const float*)d_in[0];
    const float* masks  = (const float*)d_in[1];
    const float* deltas = (const float*)d_in[2];
    const float* Wdh  = (const float*)d_in[3];
    const float* bdh  = (const float*)d_in[4];
    const float* Wdx  = (const float*)d_in[5];
    const float* bdx  = (const float*)d_in[6];
    const float* Wh   = (const float*)d_in[7];
    const float* bh   = (const float*)d_in[8];
    const float* Wf   = (const float*)d_in[9];
    const float* bf   = (const float*)d_in[10];
    const float* Wc   = (const float*)d_in[11];
    const float* bc   = (const float*)d_in[12];
    const float* W_ih = (const float*)d_in[13];
    const float* W_hh = (const float*)d_in[14];
    const float* b_ih = (const float*)d_in[15];
    const float* b_hh = (const float*)d_in[16];
    const float* Wo   = (const float*)d_in[17];
    const float* bo   = (const float*)d_in[18];

    float* denom    = (float*)d_ws;            // 48 floats
    float* out_loss = (float*)d_out;           // [0]
    float* out_imp  = out_loss + 1;            // [B*T*F]
    float* out_pred = out_imp + (size_t)BB * TT * FF;  // [B]

    denom_kernel<<<TT, NT, 0, stream>>>(masks, denom, out_loss);
    rits_kernel<<<BB / ROWS, NT, 0, stream>>>(
        values, masks, deltas, Wdh, bdh, Wdx, bdx, Wh, bh, Wf, bf, Wc, bc,
        W_ih, W_hh, b_ih, b_hh, Wo, bo, denom, out_loss, out_imp, out_pred);
}

// Round 2
// 1692.262 us; speedup vs baseline: 1.8317x; 1.8317x over previous
//
#include <hip/hip_runtime.h>
#include <hip/hip_bf16.h>
#include <math.h>

#define BB 4096
#define TT 48
#define FF 64
#define HH 128
#define ROWS 16
#define NT 512

typedef __attribute__((ext_vector_type(8))) short short8;
typedef __attribute__((ext_vector_type(4))) float f32x4;

__device__ __forceinline__ float dot4(float4 w, float4 v) {
    return fmaf(w.x, v.x, fmaf(w.y, v.y, fmaf(w.z, v.z, w.w * v.w)));
}
__device__ __forceinline__ float sigm(float x) { return 1.f / (1.f + __expf(-x)); }
__device__ __forceinline__ float tanh_f(float x) { return 2.f / (1.f + __expf(-2.f * x)) - 1.f; }

// ---- Kernel 1: denom[t] = sum(masks[:,t,:]) + 1e-5 ; zero loss slot ----
__global__ __launch_bounds__(256) void denom_kernel(const float* __restrict__ masks,
                                                    float* __restrict__ denom,
                                                    float* __restrict__ out_loss) {
    const int t = blockIdx.x;
    const int tid = threadIdx.x;
    float s = 0.f;
    for (int i = tid; i < BB * FF; i += 256) {
        int b = i >> 6, f = i & 63;
        s += masks[(b * TT + t) * FF + f];
    }
    #pragma unroll
    for (int off = 32; off; off >>= 1) s += __shfl_down(s, off, 64);
    __shared__ float red[4];
    if ((tid & 63) == 0) red[tid >> 6] = s;
    __syncthreads();
    if (tid == 0) {
        float tot = red[0] + red[1] + red[2] + red[3];
        denom[t] = tot + 1e-5f;
        if (t == 0) out_loss[0] = 0.f;
    }
}

// ---- Kernel 2: pre-format [W_ih | W_hh] as bf16 MFMA B-fragments ----
// Layout: bfrag[tile(32)][ks(8)][lane(64)][8]; n = tile*16 + (lane&15),
// k = ks*32 + (lane>>4)*8 + j ; Wcat[n][k] = k<128 ? W_ih[n][k] : W_hh[n][k-128]
__global__ __launch_bounds__(256) void prep_kernel(const float* __restrict__ W_ih,
                                                   const float* __restrict__ W_hh,
                                                   __hip_bfloat16* __restrict__ bfrag) {
    const int idx = blockIdx.x * 256 + threadIdx.x;  // < 131072
    const int j = idx & 7;
    const int lane = (idx >> 3) & 63;
    const int ks = (idx >> 9) & 7;
    const int tile = idx >> 12;
    const int n = tile * 16 + (lane & 15);
    const int k = ks * 32 + (lane >> 4) * 8 + j;
    const float v = (k < 128) ? W_ih[n * 128 + k] : W_hh[n * 128 + (k - 128)];
    bfrag[idx] = __float2bfloat16(v);
}

// ---- Main persistent kernel: each block owns 16 batch rows, all T steps ----
__global__ __launch_bounds__(NT, 1) void rits_kernel(
    const float* __restrict__ values, const float* __restrict__ masks,
    const float* __restrict__ deltas,
    const float* __restrict__ Wdh, const float* __restrict__ bdh,
    const float* __restrict__ Wdx, const float* __restrict__ bdx,
    const float* __restrict__ Wh,  const float* __restrict__ bh,
    const float* __restrict__ Wf,  const float* __restrict__ bf,
    const float* __restrict__ Wc,  const float* __restrict__ bc,
    const float* __restrict__ b_ih, const float* __restrict__ b_hh,
    const float* __restrict__ Wo,  const float* __restrict__ bo,
    const float* __restrict__ denom, const __hip_bfloat16* __restrict__ bfrag,
    float* __restrict__ out_loss, float* __restrict__ out_imp,
    float* __restrict__ out_pred)
{
    __shared__ float h_lds[ROWS][HH];     // decayed hidden state (fp32)
    __shared__ float x_lds[ROWS][FF];     // x
    __shared__ float m_lds[ROWS][FF];     // mask
    __shared__ float d_lds[ROWS][FF];     // delta; becomes x_c after phase 4
    __shared__ float xh_lds[ROWS][FF];    // x_h
    __shared__ float zh_lds[ROWS][FF];    // z_h
    __shared__ float gx_lds[ROWS][FF];    // gamma_x
    __shared__ float wfT[FF][FF];         // Wf transposed: wfT[k][f] = Wf[f][k]
    __shared__ __hip_bfloat16 abuf[ROWS][264];  // MFMA A: [c_c(0:64), m(64:128), h(128:256)], padded stride
    __shared__ float red_l[NT / 64];

    const int tid = threadIdx.x;
    const int b0 = blockIdx.x * ROWS;

    // stage Wf transposed (one-time)
    for (int i = tid; i < FF * FF; i += NT) {
        int fr = i >> 6, k = i & 63;
        wfT[k][fr] = Wf[i];
    }
    for (int i = tid; i < ROWS * HH; i += NT) ((float*)h_lds)[i] = 0.f;

    // per-thread fixed indices
    const int j   = tid & 127;   // H-dim phases
    const int jr0 = tid >> 7;    // 0..3 ; rows jr0 + 4q (q=0..3)
    const int f   = tid & 63;    // F-dim phases
    const int fr0 = tid >> 6;    // 0..7 ; rows fr0 + 8q (q=0..1)

    const float bdh_j = bdh[j];
    const float bdx_f = bdx[f];
    const float wdx_f = Wdx[f * FF + f];
    const float bh_f  = bh[f];
    const float bf_f  = bf[f];
    const float wf_dg = Wf[f * FF + f];
    const float bc_f  = bc[f];

    // MFMA lane mapping for phase 7
    const int lane = tid & 63;
    const int wv   = tid >> 6;          // wave 0..7, owns j-tile wv
    const int mA   = lane & 15;         // A-frag row
    const int quad = lane >> 4;
    const int j_ln = wv * 16 + (lane & 15);   // this lane's j (gate column)
    const float bI = b_ih[j_ln]       + b_hh[j_ln];
    const float bF = b_ih[128 + j_ln] + b_hh[128 + j_ln];
    const float bG = b_ih[256 + j_ln] + b_hh[256 + j_ln];
    const float bO = b_ih[384 + j_ln] + b_hh[384 + j_ln];

    float c_reg[4];  // LSTM cell state: rows quad*4+r, col j_ln
    #pragma unroll
    for (int r = 0; r < 4; ++r) c_reg[r] = 0.f;

    float loss_local = 0.f;
    __syncthreads();

    for (int t = 0; t < TT; ++t) {
        const float invd = 1.0f / denom[t];

        // ---- phase 1: load x, m, d ; gamma_x ; abuf m-section ----
        #pragma unroll
        for (int q = 0; q < 2; ++q) {
            const int r = fr0 + 8 * q;
            const int off = ((b0 + r) * TT + t) * FF + f;
            const float xv = values[off], mv = masks[off], dv = deltas[off];
            x_lds[r][f] = xv;
            m_lds[r][f] = mv;
            d_lds[r][f] = dv;
            gx_lds[r][f] = __expf(-fmaxf(fmaf(dv, wdx_f, bdx_f), 0.f));
            abuf[r][64 + f] = __float2bfloat16(mv);
        }
        __syncthreads();

        // ---- phase 3: gamma_h; h *= gamma_h ; abuf h-section (bf16) ----
        {
            float acc[4] = {0.f, 0.f, 0.f, 0.f};
            const float4* w4 = (const float4*)(Wdh + j * FF);
            #pragma unroll 4
            for (int kk = 0; kk < 16; ++kk) {
                const float4 w = w4[kk];
                #pragma unroll
                for (int q = 0; q < 4; ++q) {
                    const float4 dv = *(const float4*)&d_lds[jr0 + 4 * q][kk * 4];
                    acc[q] += dot4(w, dv);
                }
            }
            #pragma unroll
            for (int q = 0; q < 4; ++q) {
                const int r = jr0 + 4 * q;
                const float gh = __expf(-fmaxf(acc[q] + bdh_j, 0.f));
                const float hd = h_lds[r][j] * gh;
                h_lds[r][j] = hd;
                abuf[r][128 + j] = __float2bfloat16(hd);
            }
        }
        __syncthreads();

        float stepsum = 0.f;

        // ---- phase 4: x_h = h @ Wh.T + bh ; loss1 ; x_c -> d_lds ----
        {
            float acc[2] = {0.f, 0.f};
            const float4* w4 = (const float4*)(Wh + f * HH);
            #pragma unroll 4
            for (int kk = 0; kk < 32; ++kk) {
                const float4 w = w4[kk];
                #pragma unroll
                for (int q = 0; q < 2; ++q) {
                    const float4 hv = *(const float4*)&h_lds[fr0 + 8 * q][kk * 4];
                    acc[q] += dot4(w, hv);
                }
            }
            #pragma unroll
            for (int q = 0; q < 2; ++q) {
                const int r = fr0 + 8 * q;
                const float xh = acc[q] + bh_f;
                xh_lds[r][f] = xh;
                const float xv = x_lds[r][f], mv = m_lds[r][f];
                stepsum += mv * fabsf(xv - xh);
                d_lds[r][f] = fmaf(mv, xv, (1.f - mv) * xh);  // x_c
            }
        }
        __syncthreads();

        // ---- phase 5: z_h = x_c @ Wf_m.T + bf (zero diag) ; loss2 ----
        {
            float a0[2] = {0.f, 0.f}, a1[2] = {0.f, 0.f};
            for (int k = 0; k < 32; ++k) {
                const float w0 = wfT[k][f];
                const float w1 = wfT[k + 32][f];
                #pragma unroll
                for (int q = 0; q < 2; ++q) {
                    const int r = fr0 + 8 * q;
                    a0[q] = fmaf(d_lds[r][k], w0, a0[q]);
                    a1[q] = fmaf(d_lds[r][k + 32], w1, a1[q]);
                }
            }
            #pragma unroll
            for (int q = 0; q < 2; ++q) {
                const int r = fr0 + 8 * q;
                const float zh = a0[q] + a1[q] + bf_f - d_lds[r][f] * wf_dg;
                zh_lds[r][f] = zh;
                stepsum += m_lds[r][f] * fabsf(x_lds[r][f] - zh);
            }
        }
        __syncthreads();

        // ---- phase 6: alpha = [gamma_x, m] @ Wc.T + bc ; c_h ; loss3 ; c_c ----
        {
            float acc[2] = {0.f, 0.f};
            const float4* wc4 = (const float4*)(Wc + f * 2 * FF);
            #pragma unroll 4
            for (int kk = 0; kk < 16; ++kk) {
                const float4 w = wc4[kk];
                #pragma unroll
                for (int q = 0; q < 2; ++q) {
                    const float4 g4 = *(const float4*)&gx_lds[fr0 + 8 * q][kk * 4];
                    acc[q] += dot4(w, g4);
                }
            }
            #pragma unroll 4
            for (int kk = 0; kk < 16; ++kk) {
                const float4 w = wc4[16 + kk];
                #pragma unroll
                for (int q = 0; q < 2; ++q) {
                    const float4 m4 = *(const float4*)&m_lds[fr0 + 8 * q][kk * 4];
                    acc[q] += dot4(w, m4);
                }
            }
            #pragma unroll
            for (int q = 0; q < 2; ++q) {
                const int r = fr0 + 8 * q;
                const float alpha = acc[q] + bc_f;
                const float ch = fmaf(alpha, zh_lds[r][f], (1.f - alpha) * xh_lds[r][f]);
                const float xv = x_lds[r][f], mv = m_lds[r][f];
                stepsum += mv * fabsf(xv - ch);
                const float cc = fmaf(mv, xv, (1.f - mv) * ch);
                abuf[r][f] = __float2bfloat16(cc);
                out_imp[((b0 + r) * TT + t) * FF + f] = cc;
            }
        }
        loss_local += stepsum * invd;
        __syncthreads();

        // ---- phase 7 (MFMA): gates = [c_c,m,h] @ Wcat.T + bias ; LSTM ----
        {
            f32x4 acc[4];
            #pragma unroll
            for (int g = 0; g < 4; ++g) acc[g] = (f32x4)(0.f);
            const short8* bp = (const short8*)bfrag;
            #pragma unroll
            for (int ks = 0; ks < 8; ++ks) {
                const short8 a = *(const short8*)&abuf[mA][ks * 32 + quad * 8];
                #pragma unroll
                for (int g = 0; g < 4; ++g) {
                    const short8 b = bp[(((wv + 8 * g) * 8 + ks) << 6) + lane];
                    acc[g] = __builtin_amdgcn_mfma_f32_16x16x32_bf16(a, b, acc[g], 0, 0, 0);
                }
            }
            float hnew[4];
            #pragma unroll
            for (int r = 0; r < 4; ++r) {
                const float ig = sigm(acc[0][r] + bI);
                const float fg = sigm(acc[1][r] + bF);
                const float gg = tanh_f(acc[2][r] + bG);
                const float og = sigm(acc[3][r] + bO);
                c_reg[r] = fmaf(fg, c_reg[r], ig * gg);
                hnew[r] = og * tanh_f(c_reg[r]);
            }
            #pragma unroll
            for (int r = 0; r < 4; ++r) h_lds[quad * 4 + r][j_ln] = hnew[r];
        }
        __syncthreads();
    }

    // ---- predictions: h @ Wo.T + bo ----
    {
        const int r = tid >> 5, l = tid & 31;
        float s = 0.f;
        #pragma unroll
        for (int k = l; k < HH; k += 32) s += h_lds[r][k] * Wo[k];
        #pragma unroll
        for (int off = 16; off; off >>= 1) s += __shfl_down(s, off, 32);
        if (l == 0) out_pred[b0 + r] = s + bo[0];
    }

    // ---- loss reduce + atomic ----
    #pragma unroll
    for (int off = 32; off; off >>= 1) loss_local += __shfl_down(loss_local, off, 64);
    if ((tid & 63) == 0) red_l[tid >> 6] = loss_local;
    __syncthreads();
    if (tid == 0) {
        float tot = 0.f;
        #pragma unroll
        for (int w = 0; w < NT / 64; ++w) tot += red_l[w];
        atomicAdd(out_loss, tot);
    }
}

extern "C" void kernel_launch(void* const* d_in, const int* in_sizes, int n_in,
                              void* d_out, int out_size, void* d_ws, size_t ws_size,
                              hipStream_t stream) {
    const float* values = (const float*)d_in[0];
    const float* masks  = (const float*)d_in[1];
    const float* deltas = (const float*)d_in[2];
    const float* Wdh  = (const float*)d_in[3];
    const float* bdh  = (const float*)d_in[4];
    const float* Wdx  = (const float*)d_in[5];
    const float* bdx  = (const float*)d_in[6];
    const float* Wh   = (const float*)d_in[7];
    const float* bh   = (const float*)d_in[8];
    const float* Wf   = (const float*)d_in[9];
    const float* bf   = (const float*)d_in[10];
    const float* Wc   = (const float*)d_in[11];
    const float* bc   = (const float*)d_in[12];
    const float* W_ih = (const float*)d_in[13];
    const float* W_hh = (const float*)d_in[14];
    const float* b_ih = (const float*)d_in[15];
    const float* b_hh = (const float*)d_in[16];
    const float* Wo   = (const float*)d_in[17];
    const float* bo   = (const float*)d_in[18];

    float* denom = (float*)d_ws;                       // 48 floats
    __hip_bfloat16* bfrag = (__hip_bfloat16*)((char*)d_ws + 256);  // 131072 bf16 = 256 KB

    float* out_loss = (float*)d_out;
    float* out_imp  = out_loss + 1;
    float* out_pred = out_imp + (size_t)BB * TT * FF;

    denom_kernel<<<TT, 256, 0, stream>>>(masks, denom, out_loss);
    prep_kernel<<<512, 256, 0, stream>>>(W_ih, W_hh, bfrag);
    rits_kernel<<<BB / ROWS, NT, 0, stream>>>(
        values, masks, deltas, Wdh, bdh, Wdx, bdx, Wh, bh, Wf, bf, Wc, bc,
        b_ih, b_hh, Wo, bo, denom, bfrag, out_loss, out_imp, out_pred);
}

// Round 3
// 810.511 us; speedup vs baseline: 3.8244x; 2.0879x over previous
//
#include <hip/hip_runtime.h>
#include <hip/hip_bf16.h>
#include <math.h>

#define BB 4096
#define TT 48
#define FF 64
#define HH 128
#define ROWS 16
#define NT 512

typedef __attribute__((ext_vector_type(8))) short short8;
typedef __attribute__((ext_vector_type(4))) float f32x4;

__device__ __forceinline__ float sigm(float x) { return 1.f / (1.f + __expf(-x)); }
__device__ __forceinline__ float tanh_f(float x) { return 2.f / (1.f + __expf(-2.f * x)) - 1.f; }

// ---- Kernel 1: denom[t] = sum(masks[:,t,:]) + 1e-5 ; zero loss slot ----
__global__ __launch_bounds__(256) void denom_kernel(const float* __restrict__ masks,
                                                    float* __restrict__ denom,
                                                    float* __restrict__ out_loss) {
    const int t = blockIdx.x;
    const int tid = threadIdx.x;
    float s = 0.f;
    for (int i = tid; i < BB * FF; i += 256) {
        int b = i >> 6, f = i & 63;
        s += masks[(b * TT + t) * FF + f];
    }
    #pragma unroll
    for (int off = 32; off; off >>= 1) s += __shfl_down(s, off, 64);
    __shared__ float red[4];
    if ((tid & 63) == 0) red[tid >> 6] = s;
    __syncthreads();
    if (tid == 0) {
        float tot = red[0] + red[1] + red[2] + red[3];
        denom[t] = tot + 1e-5f;
        if (t == 0) out_loss[0] = 0.f;
    }
}

// ---- Kernel 2: pre-format ALL weights as bf16 MFMA B-fragments ----
// Fragment layout per 16x16 n-tile, per 32-k step: frag[...][lane][jj]:
//   n = nt*16 + (lane&15), k = ks*32 + (lane>>4)*8 + jj, value = W[n][k]
// Regions (element offsets into frags):
//   [0,131072)        Wcat [512][256]  (W_ih | W_hh), 32 nt x 8 ks
//   [131072,139264)   Wdh  [128][64],   8 nt x 2 ks
//   [139264,147456)   Wh   [64][128],   4 nt x 4 ks
//   [147456,151552)   Wf   [64][64] diag-zeroed, 4 nt x 2 ks
//   [151552,159744)   Wc   [64][128],   4 nt x 4 ks
__global__ __launch_bounds__(256) void prep_kernel(
    const float* __restrict__ W_ih, const float* __restrict__ W_hh,
    const float* __restrict__ Wdh,  const float* __restrict__ Wh,
    const float* __restrict__ Wf,   const float* __restrict__ Wc,
    __hip_bfloat16* __restrict__ frags) {
    const int idx = blockIdx.x * 256 + threadIdx.x;  // < 159744
    float v;
    if (idx < 131072) {
        const int jj = idx & 7;
        const int lane = (idx >> 3) & 63;
        const int ks = (idx >> 9) & 7;
        const int tile = idx >> 12;
        const int n = tile * 16 + (lane & 15);
        const int k = ks * 32 + ((lane >> 4) << 3) + jj;
        v = (k < 128) ? W_ih[n * 128 + k] : W_hh[n * 128 + (k - 128)];
    } else {
        const int u = idx - 131072;
        const int jj = u & 7;
        const int lane = (u >> 3) & 63;
        const int lq = lane & 15, q8 = (lane >> 4) << 3;
        if (u < 8192) {                       // Wdh
            const int ks = (u >> 9) & 1, nt = u >> 10;
            const int n = nt * 16 + lq, k = ks * 32 + q8 + jj;
            v = Wdh[n * 64 + k];
        } else if (u < 16384) {               // Wh
            const int uu = u - 8192;
            const int ks = (uu >> 9) & 3, nt = uu >> 11;
            const int n = nt * 16 + lq, k = ks * 32 + q8 + jj;
            v = Wh[n * 128 + k];
        } else if (u < 20480) {               // Wf (diag zero)
            const int uu = u - 16384;
            const int ks = (uu >> 9) & 1, nt = uu >> 10;
            const int n = nt * 16 + lq, k = ks * 32 + q8 + jj;
            v = (k == n) ? 0.f : Wf[n * 64 + k];
        } else {                              // Wc
            const int uu = u - 20480;
            const int ks = (uu >> 9) & 3, nt = uu >> 11;
            const int n = nt * 16 + lq, k = ks * 32 + q8 + jj;
            v = Wc[n * 128 + k];
        }
    }
    frags[idx] = __float2bfloat16(v);
}

// ---- Main persistent kernel: block = 16 batch rows (one MFMA m-tile) ----
__global__ __launch_bounds__(NT, 2) void rits_kernel(
    const float* __restrict__ values, const float* __restrict__ masks,
    const float* __restrict__ deltas,
    const float* __restrict__ Wdx, const float* __restrict__ bdx,
    const float* __restrict__ bdh, const float* __restrict__ bh,
    const float* __restrict__ bf,  const float* __restrict__ bc,
    const float* __restrict__ b_ih, const float* __restrict__ b_hh,
    const float* __restrict__ Wo,  const float* __restrict__ bo,
    const float* __restrict__ denom, const __hip_bfloat16* __restrict__ frags,
    float* __restrict__ out_loss, float* __restrict__ out_imp,
    float* __restrict__ out_pred)
{
    // A-fragment buffers, bf16, row stride padded: mult of 8 el (16B align) +
    // 4-word bank skew (2-way conflicts only = free).
    __shared__ __hip_bfloat16 dbuf[ROWS][72];    // deltas
    __shared__ __hip_bfloat16 xcbuf[ROWS][72];   // x_c
    __shared__ __hip_bfloat16 hbuf[ROWS][136];   // h (decayed / new)
    __shared__ __hip_bfloat16 gxm[ROWS][136];    // [gamma_x | m]
    __shared__ __hip_bfloat16 ccm[ROWS][136];    // [c_c | m]
    __shared__ float x_lds[ROWS][65];            // x fp32 (loss)
    __shared__ float m_lds[ROWS][65];            // m fp32 (loss)
    __shared__ float red_l[NT / 64];

    const int tid = threadIdx.x;
    const int b0 = blockIdx.x * ROWS;
    const int lane = tid & 63;
    const int wv = tid >> 6;        // wave 0..7
    const int quad = lane >> 4;
    const int lq = lane & 15;

    // zero h
    for (int i = tid; i < ROWS * 136; i += NT) ((unsigned short*)hbuf)[i] = 0;

    // p1 constants (thread owns rows wv, wv+8 at column `lane`)
    const float wdx_l = Wdx[lane * (FF + 1)];
    const float bdx_l = bdx[lane];

    // ph3 / ph7 constants (j = wv*16+lq)
    const int j_ln = wv * 16 + lq;
    const float bdh_j = bdh[j_ln];
    const float bI = b_ih[j_ln]       + b_hh[j_ln];
    const float bF = b_ih[128 + j_ln] + b_hh[128 + j_ln];
    const float bG = b_ih[256 + j_ln] + b_hh[256 + j_ln];
    const float bO = b_ih[384 + j_ln] + b_hh[384 + j_ln];

    // ph4-6 constants (waves 0-3 only; f = wv*16+lq)
    const int f46 = (wv & 3) * 16 + lq;
    const float bh_f = bh[f46];
    const float bf_f = bf[f46];
    const float bc_f = bc[f46];

    const short8* f8 = (const short8*)frags;
    // short8-unit offsets: CAT 0, DH 16384, H 17408, F 18432, C 18944

    float c_reg[4];
    #pragma unroll
    for (int r = 0; r < 4; ++r) c_reg[r] = 0.f;
    float loss_local = 0.f;

    __syncthreads();

    for (int t = 0; t < TT; ++t) {
        const float invd = 1.0f / denom[t];

        // ---- p1: load x,m,d ; gamma_x ; stage bf16 A-buffers ----
        #pragma unroll
        for (int q = 0; q < 2; ++q) {
            const int r = wv + 8 * q;
            const int off = ((b0 + r) * TT + t) * FF + lane;
            const float xv = values[off], mv = masks[off], dv = deltas[off];
            x_lds[r][lane] = xv;
            m_lds[r][lane] = mv;
            dbuf[r][lane] = __float2bfloat16(dv);
            const float gx = __expf(-fmaxf(fmaf(dv, wdx_l, bdx_l), 0.f));
            gxm[r][lane] = __float2bfloat16(gx);
            const __hip_bfloat16 mb = __float2bfloat16(mv);
            gxm[r][64 + lane] = mb;
            ccm[r][64 + lane] = mb;
        }
        __syncthreads();

        // ---- ph3 (MFMA, all 8 waves): gamma_h ; h *= gamma_h ----
        {
            f32x4 acc = {0.f, 0.f, 0.f, 0.f};
            #pragma unroll
            for (int ks = 0; ks < 2; ++ks) {
                const short8 a = *(const short8*)&dbuf[lq][ks * 32 + quad * 8];
                const short8 b = f8[16384 + ((wv * 2 + ks) << 6) + lane];
                acc = __builtin_amdgcn_mfma_f32_16x16x32_bf16(a, b, acc, 0, 0, 0);
            }
            #pragma unroll
            for (int r = 0; r < 4; ++r) {
                const int row = quad * 4 + r;
                const float gh = __expf(-fmaxf(acc[r] + bdh_j, 0.f));
                const float hd = __bfloat162float(hbuf[row][j_ln]) * gh;
                hbuf[row][j_ln] = __float2bfloat16(hd);
            }
        }
        __syncthreads();

        float xv_r[4], mv_r[4], xh_r[4];
        float stepsum = 0.f;

        // ---- ph4 (MFMA, waves 0-3): x_h ; loss1 ; x_c ----
        if (wv < 4) {
            f32x4 acc = {0.f, 0.f, 0.f, 0.f};
            #pragma unroll
            for (int ks = 0; ks < 4; ++ks) {
                const short8 a = *(const short8*)&hbuf[lq][ks * 32 + quad * 8];
                const short8 b = f8[17408 + ((wv * 4 + ks) << 6) + lane];
                acc = __builtin_amdgcn_mfma_f32_16x16x32_bf16(a, b, acc, 0, 0, 0);
            }
            #pragma unroll
            for (int r = 0; r < 4; ++r) {
                const int row = quad * 4 + r;
                const float xh = acc[r] + bh_f;
                xh_r[r] = xh;
                const float xv = x_lds[row][f46], mv = m_lds[row][f46];
                xv_r[r] = xv; mv_r[r] = mv;
                stepsum += mv * fabsf(xv - xh);
                xcbuf[row][f46] = __float2bfloat16(fmaf(mv, xv, (1.f - mv) * xh));
            }
        }
        __syncthreads();

        // ---- ph5+ph6 (MFMA, waves 0-3): z_h, alpha ; loss2+3 ; c_c ----
        if (wv < 4) {
            f32x4 acc5 = {0.f, 0.f, 0.f, 0.f};
            #pragma unroll
            for (int ks = 0; ks < 2; ++ks) {
                const short8 a = *(const short8*)&xcbuf[lq][ks * 32 + quad * 8];
                const short8 b = f8[18432 + ((wv * 2 + ks) << 6) + lane];
                acc5 = __builtin_amdgcn_mfma_f32_16x16x32_bf16(a, b, acc5, 0, 0, 0);
            }
            f32x4 acc6 = {0.f, 0.f, 0.f, 0.f};
            #pragma unroll
            for (int ks = 0; ks < 4; ++ks) {
                const short8 a = *(const short8*)&gxm[lq][ks * 32 + quad * 8];
                const short8 b = f8[18944 + ((wv * 4 + ks) << 6) + lane];
                acc6 = __builtin_amdgcn_mfma_f32_16x16x32_bf16(a, b, acc6, 0, 0, 0);
            }
            #pragma unroll
            for (int r = 0; r < 4; ++r) {
                const int row = quad * 4 + r;
                const float zh = acc5[r] + bf_f;
                stepsum += mv_r[r] * fabsf(xv_r[r] - zh);
                const float alpha = acc6[r] + bc_f;
                const float ch = fmaf(alpha, zh, (1.f - alpha) * xh_r[r]);
                stepsum += mv_r[r] * fabsf(xv_r[r] - ch);
                const float cc = fmaf(mv_r[r], xv_r[r], (1.f - mv_r[r]) * ch);
                ccm[row][f46] = __float2bfloat16(cc);
                out_imp[((b0 + row) * TT + t) * FF + f46] = cc;
            }
        }
        loss_local += stepsum * invd;
        __syncthreads();

        // ---- ph7 (MFMA, all 8 waves): gates = [c_c,m,h] @ Wcat.T ; LSTM ----
        {
            f32x4 acc[4];
            #pragma unroll
            for (int g = 0; g < 4; ++g) acc[g] = (f32x4){0.f, 0.f, 0.f, 0.f};
            #pragma unroll
            for (int ks = 0; ks < 8; ++ks) {
                const short8 a = (ks < 4)
                    ? *(const short8*)&ccm[lq][ks * 32 + quad * 8]
                    : *(const short8*)&hbuf[lq][(ks - 4) * 32 + quad * 8];
                #pragma unroll
                for (int g = 0; g < 4; ++g) {
                    const short8 b = f8[(((g * 8 + wv) * 8 + ks) << 6) + lane];
                    acc[g] = __builtin_amdgcn_mfma_f32_16x16x32_bf16(a, b, acc[g], 0, 0, 0);
                }
            }
            float hnew[4];
            #pragma unroll
            for (int r = 0; r < 4; ++r) {
                const float ig = sigm(acc[0][r] + bI);
                const float fg = sigm(acc[1][r] + bF);
                const float gg = tanh_f(acc[2][r] + bG);
                const float og = sigm(acc[3][r] + bO);
                c_reg[r] = fmaf(fg, c_reg[r], ig * gg);
                hnew[r] = og * tanh_f(c_reg[r]);
            }
            __syncthreads();  // all hbuf A-frag reads done before overwrite
            #pragma unroll
            for (int r = 0; r < 4; ++r)
                hbuf[quad * 4 + r][j_ln] = __float2bfloat16(hnew[r]);
        }
        __syncthreads();
    }

    // ---- predictions: h @ Wo.T + bo ----
    {
        const int r = tid >> 5, l = tid & 31;
        float s = 0.f;
        #pragma unroll
        for (int k = l; k < HH; k += 32) s += __bfloat162float(hbuf[r][k]) * Wo[k];
        #pragma unroll
        for (int off = 16; off; off >>= 1) s += __shfl_down(s, off, 32);
        if (l == 0) out_pred[b0 + r] = s + bo[0];
    }

    // ---- loss reduce + atomic ----
    #pragma unroll
    for (int off = 32; off; off >>= 1) loss_local += __shfl_down(loss_local, off, 64);
    if ((tid & 63) == 0) red_l[tid >> 6] = loss_local;
    __syncthreads();
    if (tid == 0) {
        float tot = 0.f;
        #pragma unroll
        for (int w = 0; w < NT / 64; ++w) tot += red_l[w];
        atomicAdd(out_loss, tot);
    }
}

extern "C" void kernel_launch(void* const* d_in, const int* in_sizes, int n_in,
                              void* d_out, int out_size, void* d_ws, size_t ws_size,
                              hipStream_t stream) {
    const float* values = (const float*)d_in[0];
    const float* masks  = (const float*)d_in[1];
    const float* deltas = (const float*)d_in[2];
    const float* Wdh  = (const float*)d_in[3];
    const float* bdh  = (const float*)d_in[4];
    const float* Wdx  = (const float*)d_in[5];
    const float* bdx  = (const float*)d_in[6];
    const float* Wh   = (const float*)d_in[7];
    const float* bh   = (const float*)d_in[8];
    const float* Wf   = (const float*)d_in[9];
    const float* bf   = (const float*)d_in[10];
    const float* Wc   = (const float*)d_in[11];
    const float* bc   = (const float*)d_in[12];
    const float* W_ih = (const float*)d_in[13];
    const float* W_hh = (const float*)d_in[14];
    const float* b_ih = (const float*)d_in[15];
    const float* b_hh = (const float*)d_in[16];
    const float* Wo   = (const float*)d_in[17];
    const float* bo   = (const float*)d_in[18];

    float* denom = (float*)d_ws;                                   // 48 floats
    __hip_bfloat16* frags = (__hip_bfloat16*)((char*)d_ws + 256);  // 159744 bf16

    float* out_loss = (float*)d_out;
    float* out_imp  = out_loss + 1;
    float* out_pred = out_imp + (size_t)BB * TT * FF;

    denom_kernel<<<TT, 256, 0, stream>>>(masks, denom, out_loss);
    prep_kernel<<<624, 256, 0, stream>>>(W_ih, W_hh, Wdh, Wh, Wf, Wc, frags);
    rits_kernel<<<BB / ROWS, NT, 0, stream>>>(
        values, masks, deltas, Wdx, bdx, bdh, bh, bf, bc,
        b_ih, b_hh, Wo, bo, denom, frags, out_loss, out_imp, out_pred);
}

// Round 4
// 378.503 us; speedup vs baseline: 8.1894x; 2.1414x over previous
//
#include <hip/hip_runtime.h>
#include <hip/hip_bf16.h>
#include <math.h>

#define BB 4096
#define TT 48
#define FF 64
#define HH 128
#define ROWS 16
#define NT 512
#define NBLK (BB / ROWS)   // 256

typedef __attribute__((ext_vector_type(8))) short short8;
typedef __attribute__((ext_vector_type(4))) float f32x4;

__device__ __forceinline__ float sigm(float x) { return 1.f / (1.f + __expf(-x)); }
__device__ __forceinline__ float tanh_f(float x) { return 2.f / (1.f + __expf(-2.f * x)) - 1.f; }

// ---- prep: pre-format ALL weights as bf16 MFMA B-fragments ----
// frag[...][lane][jj]: n = nt*16 + (lane&15), k = ks*32 + (lane>>4)*8 + jj
// Regions (element offsets):
//   [0,131072)        Wcat [512][256]  (W_ih | W_hh), 32 nt x 8 ks
//   [131072,139264)   Wdh  [128][64],   8 nt x 2 ks
//   [139264,147456)   Wh   [64][128],   4 nt x 4 ks
//   [147456,151552)   Wf   [64][64] diag-zeroed, 4 nt x 2 ks
//   [151552,159744)   Wc   [64][128],   4 nt x 4 ks
__global__ __launch_bounds__(256) void prep_kernel(
    const float* __restrict__ W_ih, const float* __restrict__ W_hh,
    const float* __restrict__ Wdh,  const float* __restrict__ Wh,
    const float* __restrict__ Wf,   const float* __restrict__ Wc,
    __hip_bfloat16* __restrict__ frags) {
    const int idx = blockIdx.x * 256 + threadIdx.x;  // < 159744
    float v;
    if (idx < 131072) {
        const int jj = idx & 7;
        const int lane = (idx >> 3) & 63;
        const int ks = (idx >> 9) & 7;
        const int tile = idx >> 12;
        const int n = tile * 16 + (lane & 15);
        const int k = ks * 32 + ((lane >> 4) << 3) + jj;
        v = (k < 128) ? W_ih[n * 128 + k] : W_hh[n * 128 + (k - 128)];
    } else {
        const int u = idx - 131072;
        const int jj = u & 7;
        const int lane = (u >> 3) & 63;
        const int lq = lane & 15, q8 = (lane >> 4) << 3;
        if (u < 8192) {                       // Wdh
            const int ks = (u >> 9) & 1, nt = u >> 10;
            const int n = nt * 16 + lq, k = ks * 32 + q8 + jj;
            v = Wdh[n * 64 + k];
        } else if (u < 16384) {               // Wh
            const int uu = u - 8192;
            const int ks = (uu >> 9) & 3, nt = uu >> 11;
            const int n = nt * 16 + lq, k = ks * 32 + q8 + jj;
            v = Wh[n * 128 + k];
        } else if (u < 20480) {               // Wf (diag zero)
            const int uu = u - 16384;
            const int ks = (uu >> 9) & 1, nt = uu >> 10;
            const int n = nt * 16 + lq, k = ks * 32 + q8 + jj;
            v = (k == n) ? 0.f : Wf[n * 64 + k];
        } else {                              // Wc
            const int uu = u - 20480;
            const int ks = (uu >> 9) & 3, nt = uu >> 11;
            const int n = nt * 16 + lq, k = ks * 32 + q8 + jj;
            v = Wc[n * 128 + k];
        }
    }
    frags[idx] = __float2bfloat16(v);
}

// ---- Main persistent kernel: block = 16 batch rows (one MFMA m-tile) ----
// Emits per-(t,block) mask sums and loss numerators to ws; no denom needed.
__global__ __launch_bounds__(NT, 2) void rits_kernel(
    const float* __restrict__ values, const float* __restrict__ masks,
    const float* __restrict__ deltas,
    const float* __restrict__ Wdx, const float* __restrict__ bdx,
    const float* __restrict__ bdh, const float* __restrict__ bh,
    const float* __restrict__ bf,  const float* __restrict__ bc,
    const float* __restrict__ b_ih, const float* __restrict__ b_hh,
    const float* __restrict__ Wo,  const float* __restrict__ bo,
    const __hip_bfloat16* __restrict__ frags,
    float* __restrict__ ws_msum,   // [TT][NBLK]
    float* __restrict__ ws_numer,  // [TT][NBLK]
    float* __restrict__ out_imp, float* __restrict__ out_pred)
{
    __shared__ __hip_bfloat16 dbuf[ROWS][72];    // deltas
    __shared__ __hip_bfloat16 xcbuf[ROWS][72];   // x_c
    __shared__ __hip_bfloat16 hbuf[ROWS][136];   // h (decayed / new)
    __shared__ __hip_bfloat16 gxm[ROWS][136];    // [gamma_x | m]
    __shared__ __hip_bfloat16 ccm[ROWS][136];    // [c_c | m]
    __shared__ float x_lds[ROWS][65];            // x fp32 (loss)
    __shared__ float m_lds[ROWS][65];            // m fp32 (loss)
    __shared__ float redm[8];                    // per-wave mask partials
    __shared__ float redl[8];                    // per-wave loss partials

    const int tid = threadIdx.x;
    const int bid = blockIdx.x;
    const int b0 = bid * ROWS;
    const int lane = tid & 63;
    const int wv = tid >> 6;        // wave 0..7
    const int quad = lane >> 4;
    const int lq = lane & 15;

    for (int i = tid; i < ROWS * 136; i += NT) ((unsigned short*)hbuf)[i] = 0;

    const float wdx_l = Wdx[lane * (FF + 1)];
    const float bdx_l = bdx[lane];

    const int j_ln = wv * 16 + lq;
    const float bdh_j = bdh[j_ln];
    const float bI = b_ih[j_ln]       + b_hh[j_ln];
    const float bF = b_ih[128 + j_ln] + b_hh[128 + j_ln];
    const float bG = b_ih[256 + j_ln] + b_hh[256 + j_ln];
    const float bO = b_ih[384 + j_ln] + b_hh[384 + j_ln];

    const int f46 = (wv & 3) * 16 + lq;
    const float bh_f = bh[f46];
    const float bf_f = bf[f46];
    const float bc_f = bc[f46];

    const short8* f8 = (const short8*)frags;
    // short8-unit offsets: CAT 0, DH 16384, H 17408, F 18432, C 18944

    float c_reg[4];
    #pragma unroll
    for (int r = 0; r < 4; ++r) c_reg[r] = 0.f;

    __syncthreads();

    for (int t = 0; t < TT; ++t) {
        // ---- p1: load x,m,d ; gamma_x ; stage bf16 A-buffers ; mask partial ----
        float msum_th = 0.f;
        #pragma unroll
        for (int q = 0; q < 2; ++q) {
            const int r = wv + 8 * q;
            const int off = ((b0 + r) * TT + t) * FF + lane;
            const float xv = values[off], mv = masks[off], dv = deltas[off];
            x_lds[r][lane] = xv;
            m_lds[r][lane] = mv;
            msum_th += mv;
            dbuf[r][lane] = __float2bfloat16(dv);
            const float gx = __expf(-fmaxf(fmaf(dv, wdx_l, bdx_l), 0.f));
            gxm[r][lane] = __float2bfloat16(gx);
            const __hip_bfloat16 mb = __float2bfloat16(mv);
            gxm[r][64 + lane] = mb;
            ccm[r][64 + lane] = mb;
        }
        #pragma unroll
        for (int off = 32; off; off >>= 1) msum_th += __shfl_down(msum_th, off, 64);
        if (lane == 0) redm[wv] = msum_th;
        __syncthreads();
        if (tid == 0) {
            float s = 0.f;
            #pragma unroll
            for (int w = 0; w < 8; ++w) s += redm[w];
            ws_msum[t * NBLK + bid] = s;
        }

        // ---- ph3 (MFMA, all 8 waves): gamma_h ; h *= gamma_h ----
        {
            f32x4 acc = {0.f, 0.f, 0.f, 0.f};
            #pragma unroll
            for (int ks = 0; ks < 2; ++ks) {
                const short8 a = *(const short8*)&dbuf[lq][ks * 32 + quad * 8];
                const short8 b = f8[16384 + ((wv * 2 + ks) << 6) + lane];
                acc = __builtin_amdgcn_mfma_f32_16x16x32_bf16(a, b, acc, 0, 0, 0);
            }
            #pragma unroll
            for (int r = 0; r < 4; ++r) {
                const int row = quad * 4 + r;
                const float gh = __expf(-fmaxf(acc[r] + bdh_j, 0.f));
                const float hd = __bfloat162float(hbuf[row][j_ln]) * gh;
                hbuf[row][j_ln] = __float2bfloat16(hd);
            }
        }
        __syncthreads();

        float xv_r[4], mv_r[4], xh_r[4];
        float stepsum = 0.f;

        // ---- ph4 (MFMA, waves 0-3): x_h ; loss1 ; x_c ----
        if (wv < 4) {
            f32x4 acc = {0.f, 0.f, 0.f, 0.f};
            #pragma unroll
            for (int ks = 0; ks < 4; ++ks) {
                const short8 a = *(const short8*)&hbuf[lq][ks * 32 + quad * 8];
                const short8 b = f8[17408 + ((wv * 4 + ks) << 6) + lane];
                acc = __builtin_amdgcn_mfma_f32_16x16x32_bf16(a, b, acc, 0, 0, 0);
            }
            #pragma unroll
            for (int r = 0; r < 4; ++r) {
                const int row = quad * 4 + r;
                const float xh = acc[r] + bh_f;
                xh_r[r] = xh;
                const float xv = x_lds[row][f46], mv = m_lds[row][f46];
                xv_r[r] = xv; mv_r[r] = mv;
                stepsum += mv * fabsf(xv - xh);
                xcbuf[row][f46] = __float2bfloat16(fmaf(mv, xv, (1.f - mv) * xh));
            }
        }
        __syncthreads();

        // ---- ph5+ph6 (MFMA, waves 0-3): z_h, alpha ; loss2+3 ; c_c ----
        if (wv < 4) {
            f32x4 acc5 = {0.f, 0.f, 0.f, 0.f};
            #pragma unroll
            for (int ks = 0; ks < 2; ++ks) {
                const short8 a = *(const short8*)&xcbuf[lq][ks * 32 + quad * 8];
                const short8 b = f8[18432 + ((wv * 2 + ks) << 6) + lane];
                acc5 = __builtin_amdgcn_mfma_f32_16x16x32_bf16(a, b, acc5, 0, 0, 0);
            }
            f32x4 acc6 = {0.f, 0.f, 0.f, 0.f};
            #pragma unroll
            for (int ks = 0; ks < 4; ++ks) {
                const short8 a = *(const short8*)&gxm[lq][ks * 32 + quad * 8];
                const short8 b = f8[18944 + ((wv * 4 + ks) << 6) + lane];
                acc6 = __builtin_amdgcn_mfma_f32_16x16x32_bf16(a, b, acc6, 0, 0, 0);
            }
            #pragma unroll
            for (int r = 0; r < 4; ++r) {
                const int row = quad * 4 + r;
                const float zh = acc5[r] + bf_f;
                stepsum += mv_r[r] * fabsf(xv_r[r] - zh);
                const float alpha = acc6[r] + bc_f;
                const float ch = fmaf(alpha, zh, (1.f - alpha) * xh_r[r]);
                stepsum += mv_r[r] * fabsf(xv_r[r] - ch);
                const float cc = fmaf(mv_r[r], xv_r[r], (1.f - mv_r[r]) * ch);
                ccm[row][f46] = __float2bfloat16(cc);
                out_imp[((b0 + row) * TT + t) * FF + f46] = cc;
            }
        }
        // per-wave loss numerator partial (waves 4-7 contribute 0)
        #pragma unroll
        for (int off = 32; off; off >>= 1) stepsum += __shfl_down(stepsum, off, 64);
        if (lane == 0) redl[wv] = stepsum;
        __syncthreads();
        if (tid == 0) {
            float s = 0.f;
            #pragma unroll
            for (int w = 0; w < 8; ++w) s += redl[w];
            ws_numer[t * NBLK + bid] = s;
        }

        // ---- ph7 (MFMA, all 8 waves): gates = [c_c,m,h] @ Wcat.T ; LSTM ----
        {
            f32x4 acc[4];
            #pragma unroll
            for (int g = 0; g < 4; ++g) acc[g] = (f32x4){0.f, 0.f, 0.f, 0.f};
            #pragma unroll
            for (int ks = 0; ks < 8; ++ks) {
                const short8 a = (ks < 4)
                    ? *(const short8*)&ccm[lq][ks * 32 + quad * 8]
                    : *(const short8*)&hbuf[lq][(ks - 4) * 32 + quad * 8];
                #pragma unroll
                for (int g = 0; g < 4; ++g) {
                    const short8 b = f8[(((g * 8 + wv) * 8 + ks) << 6) + lane];
                    acc[g] = __builtin_amdgcn_mfma_f32_16x16x32_bf16(a, b, acc[g], 0, 0, 0);
                }
            }
            float hnew[4];
            #pragma unroll
            for (int r = 0; r < 4; ++r) {
                const float ig = sigm(acc[0][r] + bI);
                const float fg = sigm(acc[1][r] + bF);
                const float gg = tanh_f(acc[2][r] + bG);
                const float og = sigm(acc[3][r] + bO);
                c_reg[r] = fmaf(fg, c_reg[r], ig * gg);
                hnew[r] = og * tanh_f(c_reg[r]);
            }
            __syncthreads();  // all hbuf A-frag reads done before overwrite
            #pragma unroll
            for (int r = 0; r < 4; ++r)
                hbuf[quad * 4 + r][j_ln] = __float2bfloat16(hnew[r]);
        }
        __syncthreads();
    }

    // ---- predictions: h @ Wo.T + bo ----
    {
        const int r = tid >> 5, l = tid & 31;
        float s = 0.f;
        #pragma unroll
        for (int k = l; k < HH; k += 32) s += __bfloat162float(hbuf[r][k]) * Wo[k];
        #pragma unroll
        for (int off = 16; off; off >>= 1) s += __shfl_down(s, off, 32);
        if (l == 0) out_pred[b0 + r] = s + bo[0];
    }
}

// ---- final: denom[t] = sum_b msum + 1e-5 ; loss = sum_t numer_t/denom_t ----
__global__ __launch_bounds__(256) void final_kernel(const float* __restrict__ ws_msum,
                                                    const float* __restrict__ ws_numer,
                                                    float* __restrict__ out_loss) {
    const int tid = threadIdx.x;
    const int lane = tid & 63, wv = tid >> 6;
    __shared__ float red[4];
    float acc = 0.f;
    for (int t = wv; t < TT; t += 4) {
        float ms = 0.f, ns = 0.f;
        #pragma unroll
        for (int c = 0; c < NBLK / 64; ++c) {
            ms += ws_msum[t * NBLK + c * 64 + lane];
            ns += ws_numer[t * NBLK + c * 64 + lane];
        }
        #pragma unroll
        for (int off = 32; off; off >>= 1) {
            ms += __shfl_down(ms, off, 64);
            ns += __shfl_down(ns, off, 64);
        }
        if (lane == 0) acc += ns / (ms + 1e-5f);
    }
    if (lane == 0) red[wv] = acc;
    __syncthreads();
    if (tid == 0) out_loss[0] = red[0] + red[1] + red[2] + red[3];
}

extern "C" void kernel_launch(void* const* d_in, const int* in_sizes, int n_in,
                              void* d_out, int out_size, void* d_ws, size_t ws_size,
                              hipStream_t stream) {
    const float* values = (const float*)d_in[0];
    const float* masks  = (const float*)d_in[1];
    const float* deltas = (const float*)d_in[2];
    const float* Wdh  = (const float*)d_in[3];
    const float* bdh  = (const float*)d_in[4];
    const float* Wdx  = (const float*)d_in[5];
    const float* bdx  = (const float*)d_in[6];
    const float* Wh   = (const float*)d_in[7];
    const float* bh   = (const float*)d_in[8];
    const float* Wf   = (const float*)d_in[9];
    const float* bf   = (const float*)d_in[10];
    const float* Wc   = (const float*)d_in[11];
    const float* bc   = (const float*)d_in[12];
    const float* W_ih = (const float*)d_in[13];
    const float* W_hh = (const float*)d_in[14];
    const float* b_ih = (const float*)d_in[15];
    const float* b_hh = (const float*)d_in[16];
    const float* Wo   = (const float*)d_in[17];
    const float* bo   = (const float*)d_in[18];

    __hip_bfloat16* frags = (__hip_bfloat16*)d_ws;                 // 159744 bf16 = 319488 B
    float* ws_msum  = (float*)((char*)d_ws + 320 * 1024);          // [48][256]
    float* ws_numer = ws_msum + TT * NBLK;                         // [48][256]

    float* out_loss = (float*)d_out;
    float* out_imp  = out_loss + 1;
    float* out_pred = out_imp + (size_t)BB * TT * FF;

    prep_kernel<<<624, 256, 0, stream>>>(W_ih, W_hh, Wdh, Wh, Wf, Wc, frags);
    rits_kernel<<<NBLK, NT, 0, stream>>>(
        values, masks, deltas, Wdx, bdx, bdh, bh, bf, bc,
        b_ih, b_hh, Wo, bo, frags, ws_msum, ws_numer, out_imp, out_pred);
    final_kernel<<<1, 256, 0, stream>>>(ws_msum, ws_numer, out_loss);
}